// Round 1
// baseline (119.628 us; speedup 1.0000x reference)
//
#include <hip/hip_runtime.h>
#include <math.h>

#define NN 1024
#define DHH 32
#define DEE 16
#define TT 8
#define NOBS_ 64
#define ADIM_ 10

__device__ __forceinline__ float sig_(float x) { return 1.0f / (1.0f + __expf(-x)); }
__device__ __forceinline__ float tanh_(float x) { return 1.0f - 2.0f / (1.0f + __expf(2.0f * x)); }

// y[i][d] = relu(h[i] . W_out[d] + b_out[d]),  16384 threads
__global__ __launch_bounds__(256) void y_kernel(const float* __restrict__ h,
                                                const float* __restrict__ W_out,
                                                const float* __restrict__ b_out,
                                                float* __restrict__ y) {
  int gid = blockIdx.x * 256 + threadIdx.x;
  int i = gid >> 4, d = gid & 15;
  const float* hp = h + i * DHH;
  const float* wp = W_out + d * DHH;
  float s = b_out[d];
#pragma unroll
  for (int q = 0; q < DHH; ++q) s = fmaf(hp[q], wp[q], s);
  y[gid] = fmaxf(s, 0.0f);
}

// base[i][k] = b_e[t_i][k] + r*w_ih_e[t_i][k][32] + sum_d w_ih_e[t_i][k][d]*y[i][d]
// gj[t][j][k] = sum_d w_ih_e[t][k][16+d]*y[j][d]
__global__ __launch_bounds__(256) void prep_kernel(const float* __restrict__ y,
                                                   const int* __restrict__ types,
                                                   const float* __restrict__ w_ih_e,
                                                   const float* __restrict__ b_e,
                                                   const float* __restrict__ rs,
                                                   float* __restrict__ base,
                                                   float* __restrict__ gj) {
  int gid = blockIdx.x * 256 + threadIdx.x;
  if (gid < NN * 48) {
    int i = gid / 48, k = gid - (gid / 48) * 48;
    int t = types[i];
    const float* w = w_ih_e + (size_t)(t * 48 + k) * 33;
    const float* yp = y + i * DEE;
    float s = b_e[t * 48 + k] + rs[0] * w[32];
#pragma unroll
    for (int q = 0; q < DEE; ++q) s = fmaf(w[q], yp[q], s);
    base[gid] = s;
  } else {
    int u = gid - NN * 48;  // u < 8*1024*48 = 393216 (grid sized exactly)
    int t = u / (NN * 48);
    int rem = u - t * (NN * 48);
    int j = rem / 48, k = rem - (rem / 48) * 48;
    const float* w = w_ih_e + (size_t)(t * 48 + k) * 33 + 16;
    const float* yp = y + j * DEE;
    float s = 0.0f;
#pragma unroll
    for (int q = 0; q < DEE; ++q) s = fmaf(w[q], yp[q], s);
    gj[u] = s;
  }
}

// One block per row i. Computes e_new for all 1024 j and rowsum[i][:] = sum_j e[i,j,:]*A[i,j].
__global__ __launch_bounds__(256) void edge_kernel(
    const float* __restrict__ e, const int* __restrict__ A,
    const float* __restrict__ w_hh_e, const float* __restrict__ bn_e,
    const int* __restrict__ types, const float* __restrict__ base,
    const float* __restrict__ gj, float* __restrict__ e_new,
    float* __restrict__ rowsum) {
  __shared__ float red[4][16];
  const int i = blockIdx.x;
  const int tid = threadIdx.x;
  const int t = types[i];  // block-uniform -> s_load
  const float* __restrict__ W = w_hh_e + (size_t)t * 48 * 16;   // uniform indices -> SGPR
  const float* __restrict__ bs = base + i * 48;                 // uniform
  const float* __restrict__ bn = bn_e + t * 16;                 // uniform
  float acc[16];
#pragma unroll
  for (int d = 0; d < 16; ++d) acc[d] = 0.0f;

  for (int jt = 0; jt < 4; ++jt) {
    const int j = jt * 256 + tid;
    const float4* ep = (const float4*)(e + ((size_t)i * NN + j) * 16);
    float4 v0 = ep[0], v1 = ep[1], v2 = ep[2], v3 = ep[3];
    float ev[16] = {v0.x, v0.y, v0.z, v0.w, v1.x, v1.y, v1.z, v1.w,
                    v2.x, v2.y, v2.z, v2.w, v3.x, v3.y, v3.z, v3.w};
    const float aij = (float)A[i * NN + j];
#pragma unroll
    for (int d = 0; d < 16; ++d) acc[d] = fmaf(ev[d], aij, acc[d]);

    const float4* gp = (const float4*)(gj + ((size_t)t * NN + j) * 48);
    float gv[48];
#pragma unroll
    for (int q = 0; q < 12; ++q) {
      float4 g = gp[q];
      gv[q * 4] = g.x; gv[q * 4 + 1] = g.y; gv[q * 4 + 2] = g.z; gv[q * 4 + 3] = g.w;
    }

    float out[16];
#pragma unroll
    for (int d = 0; d < 16; ++d) {
      float hr = 0.0f, hz = 0.0f, hn = 0.0f;
#pragma unroll
      for (int q = 0; q < 16; ++q) {
        hr = fmaf(W[d * 16 + q], ev[q], hr);
        hz = fmaf(W[(16 + d) * 16 + q], ev[q], hz);
        hn = fmaf(W[(32 + d) * 16 + q], ev[q], hn);
      }
      float rg = sig_(bs[d] + gv[d] + hr);
      float zg = sig_(bs[16 + d] + gv[16 + d] + hz);
      float ng = tanh_(bs[32 + d] + gv[32 + d] + rg * (hn + bn[d]));
      out[d] = ng + zg * (ev[d] - ng);
    }

    float* op = e_new + ((size_t)i * NN + j) * 16;  // base misaligned by 4B -> scalar dword stores
#pragma unroll
    for (int d = 0; d < 16; ++d) op[d] = out[d];
  }

  // block reduction of acc -> rowsum[i]
#pragma unroll
  for (int d = 0; d < 16; ++d) {
    float v = acc[d];
#pragma unroll
    for (int off = 32; off >= 1; off >>= 1) v += __shfl_down(v, off, 64);
    acc[d] = v;
  }
  const int lane = tid & 63, wid = tid >> 6;
  if (lane == 0) {
#pragma unroll
    for (int d = 0; d < 16; ++d) red[wid][d] = acc[d];
  }
  __syncthreads();
  if (tid < 16)
    rowsum[i * 16 + tid] = red[0][tid] + red[1][tid] + red[2][tid] + red[3][tid];
}

// Node GRU (32 threads per node, 8 nodes per block) + argmax in block 0 thread 0.
__global__ __launch_bounds__(256) void node_kernel(
    const float* __restrict__ obs, const float* __restrict__ h,
    const int* __restrict__ types, const float* __restrict__ w_ih_n,
    const float* __restrict__ w_hh_n, const float* __restrict__ b_n,
    const float* __restrict__ bn_n, const float* __restrict__ y,
    const float* __restrict__ rowsum, float* __restrict__ out) {
  const int tid = threadIdx.x;
  const int node = blockIdx.x * 8 + (tid >> 5);
  const int d = tid & 31;
  const int t = types[node];
  float x[16];
#pragma unroll
  for (int q = 0; q < 16; ++q) x[q] = y[node * 16 + q] * rowsum[node * 16 + q];
  if (node < NOBS_) x[0] = obs[node];
  const float* wi = w_ih_n + (size_t)t * 96 * 16;
  const float* wh = w_hh_n + (size_t)t * 96 * 32;
  const float* hp = h + node * 32;
  float ir = b_n[t * 96 + d], iz = b_n[t * 96 + 32 + d], in_ = b_n[t * 96 + 64 + d];
#pragma unroll
  for (int q = 0; q < 16; ++q) {
    ir = fmaf(wi[d * 16 + q], x[q], ir);
    iz = fmaf(wi[(32 + d) * 16 + q], x[q], iz);
    in_ = fmaf(wi[(64 + d) * 16 + q], x[q], in_);
  }
  float hr = 0.0f, hz = 0.0f, hn = 0.0f;
#pragma unroll
  for (int q = 0; q < 32; ++q) {
    hr = fmaf(wh[d * 32 + q], hp[q], hr);
    hz = fmaf(wh[(32 + d) * 32 + q], hp[q], hz);
    hn = fmaf(wh[(64 + d) * 32 + q], hp[q], hn);
  }
  float rg = sig_(ir + hr), zg = sig_(iz + hz);
  float ng = tanh_(in_ + rg * (hn + bn_n[t * 32 + d]));
  out[1 + node * 32 + d] = ng + zg * (hp[d] - ng);

  if (blockIdx.x == 0 && tid == 0) {
    int bi = 0;
    float best = y[(NN - ADIM_) * 16];
    for (int l = 1; l < ADIM_; ++l) {
      float v = y[(NN - ADIM_ + l) * 16];
      if (v > best) { best = v; bi = l; }
    }
    out[0] = (float)bi;
  }
}

extern "C" void kernel_launch(void* const* d_in, const int* in_sizes, int n_in,
                              void* d_out, int out_size, void* d_ws, size_t ws_size,
                              hipStream_t stream) {
  const float* obs   = (const float*)d_in[0];
  const float* h     = (const float*)d_in[1];
  const int*   types = (const int*)d_in[2];
  const float* e     = (const float*)d_in[3];
  const int*   A     = (const int*)d_in[4];
  const float* r     = (const float*)d_in[5];
  const float* w_ih_n = (const float*)d_in[6];
  const float* w_hh_n = (const float*)d_in[7];
  const float* b_n    = (const float*)d_in[8];
  const float* bn_n   = (const float*)d_in[9];
  const float* W_out  = (const float*)d_in[10];
  const float* b_out  = (const float*)d_in[11];
  const float* w_ih_e = (const float*)d_in[12];
  const float* w_hh_e = (const float*)d_in[13];
  const float* b_e    = (const float*)d_in[14];
  const float* bn_e   = (const float*)d_in[15];

  float* ws = (float*)d_ws;
  float* y_buf   = ws;                     // 1024*16   = 16384
  float* base    = y_buf + 16384;          // 1024*48   = 49152
  float* gj      = base + 49152;           // 8*1024*48 = 393216
  float* rowsum  = gj + 393216;            // 1024*16   = 16384

  float* out   = (float*)d_out;
  float* out_e = out + 1 + NN * DHH;       // e_new region (d_out + 32769)

  y_kernel<<<64, 256, 0, stream>>>(h, W_out, b_out, y_buf);
  prep_kernel<<<1728, 256, 0, stream>>>(y_buf, types, w_ih_e, b_e, r, base, gj);
  edge_kernel<<<NN, 256, 0, stream>>>(e, A, w_hh_e, bn_e, types, base, gj, out_e, rowsum);
  node_kernel<<<128, 256, 0, stream>>>(obs, h, types, w_ih_n, w_hh_n, b_n, bn_n,
                                       y_buf, rowsum, out);
}

// Round 2
// 101.315 us; speedup vs baseline: 1.1808x; 1.1808x over previous
//
#include <hip/hip_runtime.h>
#include <math.h>

#define NN 1024
#define DHH 32
#define DEE 16
#define TT 8
#define NOBS_ 64
#define ADIM_ 10
#define NSPLIT 4   // blocks per row in edge kernel

__device__ __forceinline__ float sig_(float x) { return 1.0f / (1.0f + __expf(-x)); }
__device__ __forceinline__ float tanh_(float x) { return 1.0f - 2.0f / (1.0f + __expf(2.0f * x)); }

// y[i][d] = relu(h[i] . W_out[d] + b_out[d]),  16384 threads
__global__ __launch_bounds__(256) void y_kernel(const float* __restrict__ h,
                                                const float* __restrict__ W_out,
                                                const float* __restrict__ b_out,
                                                float* __restrict__ y) {
  int gid = blockIdx.x * 256 + threadIdx.x;
  int i = gid >> 4, d = gid & 15;
  const float* hp = h + i * DHH;
  const float* wp = W_out + d * DHH;
  float s = b_out[d];
#pragma unroll
  for (int q = 0; q < DHH; ++q) s = fmaf(hp[q], wp[q], s);
  y[gid] = fmaxf(s, 0.0f);
}

// base[i][k] = b_e[t_i][k] + r*w_ih_e[t_i][k][32] + sum_d w_ih_e[t_i][k][d]*y[i][d]
// gj[t][j][k] = sum_d w_ih_e[t][k][16+d]*y[j][d]
__global__ __launch_bounds__(256) void prep_kernel(const float* __restrict__ y,
                                                   const int* __restrict__ types,
                                                   const float* __restrict__ w_ih_e,
                                                   const float* __restrict__ b_e,
                                                   const float* __restrict__ rs,
                                                   float* __restrict__ base,
                                                   float* __restrict__ gj) {
  int gid = blockIdx.x * 256 + threadIdx.x;
  if (gid < NN * 48) {
    int i = gid / 48, k = gid - (gid / 48) * 48;
    int t = types[i];
    const float* w = w_ih_e + (size_t)(t * 48 + k) * 33;
    const float* yp = y + i * DEE;
    float s = b_e[t * 48 + k] + rs[0] * w[32];
#pragma unroll
    for (int q = 0; q < DEE; ++q) s = fmaf(w[q], yp[q], s);
    base[gid] = s;
  } else {
    int u = gid - NN * 48;  // u < 8*1024*48 = 393216 (grid sized exactly)
    int t = u / (NN * 48);
    int rem = u - t * (NN * 48);
    int j = rem / 48, k = rem - (rem / 48) * 48;
    const float* w = w_ih_e + (size_t)(t * 48 + k) * 33 + 16;
    const float* yp = y + j * DEE;
    float s = 0.0f;
#pragma unroll
    for (int q = 0; q < DEE; ++q) s = fmaf(w[q], yp[q], s);
    gj[u] = s;
  }
}

// d-split edge GRU: block b handles row i = b/NSPLIT, j-range s = b%NSPLIT.
// Thread owns output dim d = tid&15 for 16 edges; its 48 W values live in VGPRs.
__global__ __launch_bounds__(256, 4) void edge_kernel(
    const float* __restrict__ e, const int* __restrict__ A,
    const float* __restrict__ w_hh_e, const float* __restrict__ bn_e,
    const int* __restrict__ types, const float* __restrict__ base,
    const float* __restrict__ gj, float* __restrict__ e_new,
    float* __restrict__ rowsum_part) {
  __shared__ float red[4][16];
  const int b = blockIdx.x;
  const int i = b >> 2;          // row
  const int s = b & 3;           // j-range split
  const int tid = threadIdx.x;
  const int d = tid & 15;
  const int jloc = tid >> 4;     // 0..15
  const int t = types[i];        // block-uniform

  // hoist this thread's 3 weight rows (reset/update/new for output dim d)
  const float* W = w_hh_e + (size_t)t * 768;
  float wr[16], wz[16], wn[16];
  {
    const float4* r4 = (const float4*)(W + d * 16);
    const float4* z4 = (const float4*)(W + (16 + d) * 16);
    const float4* n4 = (const float4*)(W + (32 + d) * 16);
#pragma unroll
    for (int q = 0; q < 4; ++q) {
      float4 a = r4[q], bq = z4[q], c = n4[q];
      wr[q * 4] = a.x; wr[q * 4 + 1] = a.y; wr[q * 4 + 2] = a.z; wr[q * 4 + 3] = a.w;
      wz[q * 4] = bq.x; wz[q * 4 + 1] = bq.y; wz[q * 4 + 2] = bq.z; wz[q * 4 + 3] = bq.w;
      wn[q * 4] = c.x; wn[q * 4 + 1] = c.y; wn[q * 4 + 2] = c.z; wn[q * 4 + 3] = c.w;
    }
  }
  const float bsr = base[i * 48 + d];
  const float bsz = base[i * 48 + 16 + d];
  const float bsn = base[i * 48 + 32 + d];
  const float bnd = bn_e[t * 16 + d];

  float accd = 0.0f;
  const int jbase = s * 256 + jloc;
  for (int k = 0; k < 16; ++k) {
    const int j = jbase + k * 16;
    const size_t eoff = ((size_t)i * NN + j) * 16;
    const float4* ep = (const float4*)(e + eoff);
    float4 v0 = ep[0], v1 = ep[1], v2 = ep[2], v3 = ep[3];
    float ev[16] = {v0.x, v0.y, v0.z, v0.w, v1.x, v1.y, v1.z, v1.w,
                    v2.x, v2.y, v2.z, v2.w, v3.x, v3.y, v3.z, v3.w};
    const float evd = e[eoff + d];              // coalesced scalar pick of own dim
    const float aij = (float)A[i * NN + j];
    accd = fmaf(evd, aij, accd);

    const float* gp = gj + ((size_t)t * NN + j) * 48;
    const float g0 = gp[d], g1 = gp[16 + d], g2 = gp[32 + d];

    float hr = 0.0f, hz = 0.0f, hn = 0.0f;
#pragma unroll
    for (int q = 0; q < 16; ++q) {
      hr = fmaf(wr[q], ev[q], hr);
      hz = fmaf(wz[q], ev[q], hz);
      hn = fmaf(wn[q], ev[q], hn);
    }
    const float rg = sig_(bsr + g0 + hr);
    const float zg = sig_(bsz + g1 + hz);
    const float ng = tanh_(bsn + g2 + rg * (hn + bnd));
    e_new[eoff + d] = ng + zg * (evd - ng);
  }

  // reduce accd: lanes {d, d^16, d^32, d^48} of each wave share d
  float v = accd;
  v += __shfl_xor(v, 16, 64);
  v += __shfl_xor(v, 32, 64);
  const int lane = tid & 63, wid = tid >> 6;
  if (lane < 16) red[wid][lane] = v;
  __syncthreads();
  if (tid < 16)
    rowsum_part[((size_t)i * NSPLIT + s) * 16 + tid] =
        red[0][tid] + red[1][tid] + red[2][tid] + red[3][tid];
}

// Node GRU (32 threads per node, 8 nodes per block) + argmax in block 0 thread 0.
__global__ __launch_bounds__(256) void node_kernel(
    const float* __restrict__ obs, const float* __restrict__ h,
    const int* __restrict__ types, const float* __restrict__ w_ih_n,
    const float* __restrict__ w_hh_n, const float* __restrict__ b_n,
    const float* __restrict__ bn_n, const float* __restrict__ y,
    const float* __restrict__ rowsum_part, float* __restrict__ out) {
  const int tid = threadIdx.x;
  const int node = blockIdx.x * 8 + (tid >> 5);
  const int d = tid & 31;
  const int t = types[node];
  float x[16];
#pragma unroll
  for (int q = 0; q < 16; ++q) {
    const float* rp = rowsum_part + (size_t)node * NSPLIT * 16 + q;
    float rs = rp[0] + rp[16] + rp[32] + rp[48];
    x[q] = y[node * 16 + q] * rs;
  }
  if (node < NOBS_) x[0] = obs[node];
  const float* wi = w_ih_n + (size_t)t * 96 * 16;
  const float* wh = w_hh_n + (size_t)t * 96 * 32;
  const float* hp = h + node * 32;
  float ir = b_n[t * 96 + d], iz = b_n[t * 96 + 32 + d], in_ = b_n[t * 96 + 64 + d];
#pragma unroll
  for (int q = 0; q < 16; ++q) {
    ir = fmaf(wi[d * 16 + q], x[q], ir);
    iz = fmaf(wi[(32 + d) * 16 + q], x[q], iz);
    in_ = fmaf(wi[(64 + d) * 16 + q], x[q], in_);
  }
  float hr = 0.0f, hz = 0.0f, hn = 0.0f;
#pragma unroll
  for (int q = 0; q < 32; ++q) {
    hr = fmaf(wh[d * 32 + q], hp[q], hr);
    hz = fmaf(wh[(32 + d) * 32 + q], hp[q], hz);
    hn = fmaf(wh[(64 + d) * 32 + q], hp[q], hn);
  }
  float rg = sig_(ir + hr), zg = sig_(iz + hz);
  float ng = tanh_(in_ + rg * (hn + bn_n[t * 32 + d]));
  out[1 + node * 32 + d] = ng + zg * (hp[d] - ng);

  if (blockIdx.x == 0 && tid == 0) {
    int bi = 0;
    float best = y[(NN - ADIM_) * 16];
    for (int l = 1; l < ADIM_; ++l) {
      float v = y[(NN - ADIM_ + l) * 16];
      if (v > best) { best = v; bi = l; }
    }
    out[0] = (float)bi;
  }
}

extern "C" void kernel_launch(void* const* d_in, const int* in_sizes, int n_in,
                              void* d_out, int out_size, void* d_ws, size_t ws_size,
                              hipStream_t stream) {
  const float* obs   = (const float*)d_in[0];
  const float* h     = (const float*)d_in[1];
  const int*   types = (const int*)d_in[2];
  const float* e     = (const float*)d_in[3];
  const int*   A     = (const int*)d_in[4];
  const float* r     = (const float*)d_in[5];
  const float* w_ih_n = (const float*)d_in[6];
  const float* w_hh_n = (const float*)d_in[7];
  const float* b_n    = (const float*)d_in[8];
  const float* bn_n   = (const float*)d_in[9];
  const float* W_out  = (const float*)d_in[10];
  const float* b_out  = (const float*)d_in[11];
  const float* w_ih_e = (const float*)d_in[12];
  const float* w_hh_e = (const float*)d_in[13];
  const float* b_e    = (const float*)d_in[14];
  const float* bn_e   = (const float*)d_in[15];

  float* ws = (float*)d_ws;
  float* y_buf       = ws;                     // 1024*16        = 16384
  float* base        = y_buf + 16384;          // 1024*48        = 49152
  float* gj          = base + 49152;           // 8*1024*48      = 393216
  float* rowsum_part = gj + 393216;            // 1024*4*16      = 65536

  float* out   = (float*)d_out;
  float* out_e = out + 1 + NN * DHH;           // e_new region (d_out + 32769)

  y_kernel<<<64, 256, 0, stream>>>(h, W_out, b_out, y_buf);
  prep_kernel<<<1728, 256, 0, stream>>>(y_buf, types, w_ih_e, b_e, r, base, gj);
  edge_kernel<<<NN * NSPLIT, 256, 0, stream>>>(e, A, w_hh_e, bn_e, types, base, gj,
                                               out_e, rowsum_part);
  node_kernel<<<128, 256, 0, stream>>>(obs, h, types, w_ih_n, w_hh_n, b_n, bn_n,
                                       y_buf, rowsum_part, out);
}

// Round 3
// 58.162 us; speedup vs baseline: 2.0568x; 1.7419x over previous
//
#include <hip/hip_runtime.h>
#include <math.h>

#define NN 1024
#define DHH 32
#define DEE 16
#define TT 8
#define NOBS_ 64
#define ADIM_ 10
#define NSPLIT 2   // blocks per row in edge kernel

typedef _Float16 h4 __attribute__((ext_vector_type(4)));
typedef float f4 __attribute__((ext_vector_type(4)));

__device__ __forceinline__ float sig_(float x) { return 1.0f / (1.0f + __expf(-x)); }
__device__ __forceinline__ float tanh_(float x) { return 1.0f - 2.0f / (1.0f + __expf(2.0f * x)); }

// y[i][d] = relu(h[i] . W_out[d] + b_out[d]),  16384 threads
__global__ __launch_bounds__(256) void y_kernel(const float* __restrict__ h,
                                                const float* __restrict__ W_out,
                                                const float* __restrict__ b_out,
                                                float* __restrict__ y) {
  int gid = blockIdx.x * 256 + threadIdx.x;
  int i = gid >> 4, d = gid & 15;
  const float* hp = h + i * DHH;
  const float* wp = W_out + d * DHH;
  float s = b_out[d];
#pragma unroll
  for (int q = 0; q < DHH; ++q) s = fmaf(hp[q], wp[q], s);
  y[gid] = fmaxf(s, 0.0f);
}

// base[i][k] = b_e[t_i][k] + r*w_ih_e[t_i][k][32] + sum_d w_ih_e[t_i][k][d]*y[i][d]
// gj[t][j][k] = sum_d w_ih_e[t][k][16+d]*y[j][d]
__global__ __launch_bounds__(256) void prep_kernel(const float* __restrict__ y,
                                                   const int* __restrict__ types,
                                                   const float* __restrict__ w_ih_e,
                                                   const float* __restrict__ b_e,
                                                   const float* __restrict__ rs,
                                                   float* __restrict__ base,
                                                   float* __restrict__ gj) {
  int gid = blockIdx.x * 256 + threadIdx.x;
  if (gid < NN * 48) {
    int i = gid / 48, k = gid - (gid / 48) * 48;
    int t = types[i];
    const float* w = w_ih_e + (size_t)(t * 48 + k) * 33;
    const float* yp = y + i * DEE;
    float s = b_e[t * 48 + k] + rs[0] * w[32];
#pragma unroll
    for (int q = 0; q < DEE; ++q) s = fmaf(w[q], yp[q], s);
    base[gid] = s;
  } else {
    int u = gid - NN * 48;  // u < 8*1024*48 = 393216 (grid sized exactly)
    int t = u / (NN * 48);
    int rem = u - t * (NN * 48);
    int j = rem / 48, k = rem - (rem / 48) * 48;
    const float* w = w_ih_e + (size_t)(t * 48 + k) * 33 + 16;
    const float* yp = y + j * DEE;
    float s = 0.0f;
#pragma unroll
    for (int q = 0; q < DEE; ++q) s = fmaf(w[q], yp[q], s);
    gj[u] = s;
  }
}

// MFMA edge GRU. Block b: row i = b>>1, j-half s = b&1. 4 waves, each wave 8 tiles of 16 j.
// Per tile: D[48x16] = W[48x16] (A-frag, f16) x e^T[16x16] (B-frag, f16), 3 MFMAs (gates).
// D layout: lane holds edge j0+(lane&15), dims (lane>>4)*4+q  -> gates in float4, coalesced.
__global__ __launch_bounds__(256) void edge_kernel(
    const float* __restrict__ e, const int* __restrict__ A,
    const float* __restrict__ w_hh_e, const float* __restrict__ bn_e,
    const int* __restrict__ types, const float* __restrict__ base,
    const float* __restrict__ gj, float* __restrict__ e_new,
    float* __restrict__ rowsum_part) {
  __shared__ float red[4][16];
  const int b = blockIdx.x;
  const int i = b >> 1;
  const int s = b & 1;
  const int tid = threadIdx.x;
  const int lane = tid & 63, wid = tid >> 6;
  const int lj = lane & 15;   // M-index for A-frag / N(edge)-index for B,D frags
  const int kg = lane >> 4;   // K-chunk (A,B) / M(dim)-chunk (D)
  const int t = types[i];

  // A-frags: lane holds W[gate*16 + lj][kg*4 + q], q=0..3 (contiguous float4 -> f16)
  const float* Wt = w_hh_e + (size_t)t * 768;
  h4 ar, az, an;
  {
    f4 vr = *(const f4*)(Wt + (lj) * 16 + kg * 4);
    f4 vz = *(const f4*)(Wt + (16 + lj) * 16 + kg * 4);
    f4 vn = *(const f4*)(Wt + (32 + lj) * 16 + kg * 4);
#pragma unroll
    for (int q = 0; q < 4; ++q) {
      ar[q] = (_Float16)vr[q]; az[q] = (_Float16)vz[q]; an[q] = (_Float16)vn[q];
    }
  }
  // per-lane gate constants for dims kg*4+q (the D-rows this lane owns)
  const f4 bsr = *(const f4*)(base + i * 48 + kg * 4);
  const f4 bsz = *(const f4*)(base + i * 48 + 16 + kg * 4);
  const f4 bsn = *(const f4*)(base + i * 48 + 32 + kg * 4);
  const f4 bnv = *(const f4*)(bn_e + t * 16 + kg * 4);

  f4 acc = {0.0f, 0.0f, 0.0f, 0.0f};
  const f4 zero = {0.0f, 0.0f, 0.0f, 0.0f};

  for (int tt = 0; tt < 8; ++tt) {
    const int j = s * 512 + wid * 128 + tt * 16 + lj;
    const size_t eoff = ((size_t)i * NN + j) * 16 + kg * 4;
    const f4 ev = *(const f4*)(e + eoff);           // = B-frag data AND evd AND rowsum input
    h4 bf;
#pragma unroll
    for (int q = 0; q < 4; ++q) bf[q] = (_Float16)ev[q];

    f4 dr = __builtin_amdgcn_mfma_f32_16x16x16f16(ar, bf, zero, 0, 0, 0);
    f4 dz = __builtin_amdgcn_mfma_f32_16x16x16f16(az, bf, zero, 0, 0, 0);
    f4 dn = __builtin_amdgcn_mfma_f32_16x16x16f16(an, bf, zero, 0, 0, 0);

    const float aij = (float)A[i * NN + j];
#pragma unroll
    for (int q = 0; q < 4; ++q) acc[q] = fmaf(ev[q], aij, acc[q]);

    const float* gp = gj + ((size_t)t * NN + j) * 48 + kg * 4;
    const f4 gr = *(const f4*)(gp);
    const f4 gz = *(const f4*)(gp + 16);
    const f4 gn = *(const f4*)(gp + 32);

    float* op = e_new + eoff;   // base misaligned by 4B -> scalar dword stores
#pragma unroll
    for (int q = 0; q < 4; ++q) {
      const float rg = sig_(bsr[q] + gr[q] + dr[q]);
      const float zg = sig_(bsz[q] + gz[q] + dz[q]);
      const float ng = tanh_(bsn[q] + gn[q] + rg * (dn[q] + bnv[q]));
      op[q] = ng + zg * (ev[q] - ng);
    }
  }

  // acc[q] = partial sum over this lane's 8 j's of e[i][j][kg*4+q]*A[i][j].
  // Reduce over the 16 lanes of each kg-group (xor 1,2,4,8 stays in-group).
#pragma unroll
  for (int m = 1; m <= 8; m <<= 1) {
#pragma unroll
    for (int q = 0; q < 4; ++q) acc[q] += __shfl_xor(acc[q], m, 64);
  }
  if (lj == 0) {
#pragma unroll
    for (int q = 0; q < 4; ++q) red[wid][kg * 4 + q] = acc[q];
  }
  __syncthreads();
  if (tid < 16)
    rowsum_part[((size_t)i * NSPLIT + s) * 16 + tid] =
        red[0][tid] + red[1][tid] + red[2][tid] + red[3][tid];
}

// Node GRU (32 threads per node, 8 nodes per block) + argmax in block 0 thread 0.
__global__ __launch_bounds__(256) void node_kernel(
    const float* __restrict__ obs, const float* __restrict__ h,
    const int* __restrict__ types, const float* __restrict__ w_ih_n,
    const float* __restrict__ w_hh_n, const float* __restrict__ b_n,
    const float* __restrict__ bn_n, const float* __restrict__ y,
    const float* __restrict__ rowsum_part, float* __restrict__ out) {
  const int tid = threadIdx.x;
  const int node = blockIdx.x * 8 + (tid >> 5);
  const int d = tid & 31;
  const int t = types[node];
  float x[16];
#pragma unroll
  for (int q = 0; q < 16; ++q) {
    const float* rp = rowsum_part + (size_t)node * NSPLIT * 16 + q;
    float rs = rp[0] + rp[16];
    x[q] = y[node * 16 + q] * rs;
  }
  if (node < NOBS_) x[0] = obs[node];
  const float* wi = w_ih_n + (size_t)t * 96 * 16;
  const float* wh = w_hh_n + (size_t)t * 96 * 32;
  const float* hp = h + node * 32;
  float ir = b_n[t * 96 + d], iz = b_n[t * 96 + 32 + d], in_ = b_n[t * 96 + 64 + d];
#pragma unroll
  for (int q = 0; q < 16; ++q) {
    ir = fmaf(wi[d * 16 + q], x[q], ir);
    iz = fmaf(wi[(32 + d) * 16 + q], x[q], iz);
    in_ = fmaf(wi[(64 + d) * 16 + q], x[q], in_);
  }
  float hr = 0.0f, hz = 0.0f, hn = 0.0f;
#pragma unroll
  for (int q = 0; q < 32; ++q) {
    hr = fmaf(wh[d * 32 + q], hp[q], hr);
    hz = fmaf(wh[(32 + d) * 32 + q], hp[q], hz);
    hn = fmaf(wh[(64 + d) * 32 + q], hp[q], hn);
  }
  float rg = sig_(ir + hr), zg = sig_(iz + hz);
  float ng = tanh_(in_ + rg * (hn + bn_n[t * 32 + d]));
  out[1 + node * 32 + d] = ng + zg * (hp[d] - ng);

  if (blockIdx.x == 0 && tid == 0) {
    int bi = 0;
    float best = y[(NN - ADIM_) * 16];
    for (int l = 1; l < ADIM_; ++l) {
      float v = y[(NN - ADIM_ + l) * 16];
      if (v > best) { best = v; bi = l; }
    }
    out[0] = (float)bi;
  }
}

extern "C" void kernel_launch(void* const* d_in, const int* in_sizes, int n_in,
                              void* d_out, int out_size, void* d_ws, size_t ws_size,
                              hipStream_t stream) {
  const float* obs   = (const float*)d_in[0];
  const float* h     = (const float*)d_in[1];
  const int*   types = (const int*)d_in[2];
  const float* e     = (const float*)d_in[3];
  const int*   A     = (const int*)d_in[4];
  const float* r     = (const float*)d_in[5];
  const float* w_ih_n = (const float*)d_in[6];
  const float* w_hh_n = (const float*)d_in[7];
  const float* b_n    = (const float*)d_in[8];
  const float* bn_n   = (const float*)d_in[9];
  const float* W_out  = (const float*)d_in[10];
  const float* b_out  = (const float*)d_in[11];
  const float* w_ih_e = (const float*)d_in[12];
  const float* w_hh_e = (const float*)d_in[13];
  const float* b_e    = (const float*)d_in[14];
  const float* bn_e   = (const float*)d_in[15];

  float* ws = (float*)d_ws;
  float* y_buf       = ws;                     // 1024*16        = 16384
  float* base        = y_buf + 16384;          // 1024*48        = 49152
  float* gj          = base + 49152;           // 8*1024*48     = 393216
  float* rowsum_part = gj + 393216;            // 1024*2*16      = 32768

  float* out   = (float*)d_out;
  float* out_e = out + 1 + NN * DHH;           // e_new region (d_out + 32769)

  y_kernel<<<64, 256, 0, stream>>>(h, W_out, b_out, y_buf);
  prep_kernel<<<1728, 256, 0, stream>>>(y_buf, types, w_ih_e, b_e, r, base, gj);
  edge_kernel<<<NN * NSPLIT, 256, 0, stream>>>(e, A, w_hh_e, bn_e, types, base, gj,
                                               out_e, rowsum_part);
  node_kernel<<<128, 256, 0, stream>>>(obs, h, types, w_ih_n, w_hh_n, b_n, bn_n,
                                       y_buf, rowsum_part, out);
}